// Round 2
// baseline (247.208 us; speedup 1.0000x reference)
//
#include <hip/hip_runtime.h>
#include <stdint.h>

#define N_ANCH 65648
#define NCHUNK 17          // ceil(65648/4096)
#define CHUNK  4096
#define CAP    4096        // candidate capacity per batch (LDS)
#define KBASE  0xBE800000u // sortable key of score 0.25 (all fg scores >= 1/3)
#define NBATCH 32
#define TOPK   100

struct Ptrs { const float* cls[8]; const float* reg[8]; };

__constant__ int   c_off[9] = {0,25281,50562,56803,63044,64565,64926,65287,65648};
__constant__ int   c_sz[8]  = {159,159,79,79,39,19,19,19};
__constant__ float c_st[8]  = {4.f,4.f,8.f,8.f,16.f,32.f,32.f,32.f};
__constant__ float c_rf[8]  = {27.5f,35.5f,55.5f,71.5f,111.5f,191.5f,255.5f,319.5f};

// sortable key for the masked score of anchor n in batch b; 0 if background
__device__ inline uint32_t anchor_key(const Ptrs& p, int b, int n) {
  int k = 0;
#pragma unroll
  for (int q = 1; q < 8; ++q) if (n >= c_off[q]) k = q;
  int local = n - c_off[k];
  int hw = c_sz[k] * c_sz[k];
  const float* c = p.cls[k] + (size_t)(b * 3) * hw + local;
  float l0 = c[0], l1 = c[(size_t)hw], l2 = c[(size_t)2 * hw];
  float m = l0; int cl = 0;
  if (l1 > m) { m = l1; cl = 1; }
  if (l2 > m) { m = l2; cl = 2; }
  if (cl == 0) return 0u;                 // background -> masked score -1
  float s = 1.0f / (expf(l0 - m) + expf(l1 - m) + expf(l2 - m));
  return __float_as_uint(s) | 0x80000000u; // positive float -> monotonic uint
}

// Pass 1: per-(batch,chunk) private histogram — pure stores, no pre-zero needed
__global__ __launch_bounds__(256) void k_hist(Ptrs p, uint32_t* hist) {
  int bid = blockIdx.x;
  int b = bid / NCHUNK, chunk = bid % NCHUNK;
  __shared__ uint32_t lh[256];
  lh[threadIdx.x] = 0;
  __syncthreads();
  int n0 = chunk * CHUNK;
  for (int t = threadIdx.x; t < CHUNK; t += 256) {
    int n = n0 + t;
    if (n < N_ANCH) {
      uint32_t key = anchor_key(p, b, n);
      if (key >= KBASE) atomicAdd(&lh[(key - KBASE) >> 16], 1u);
    }
  }
  __syncthreads();
  hist[((size_t)b * NCHUNK + chunk) * 256 + threadIdx.x] = lh[threadIdx.x];
}

// Pass 2: one block per batch — threshold, collect (LDS), sort, decode, NMS, output
__global__ __launch_bounds__(256) void k_final(Ptrs p, const uint32_t* hist, float* out) {
  int b = blockIdx.x;
  int t = threadIdx.x;
  __shared__ uint32_t tot[256];
  __shared__ unsigned long long s[CAP];
  __shared__ float bx1[TOPK], by1[TOPK], bx2[TOPK], by2[TOPK], area[TOPK], sc[TOPK];
  __shared__ int cls_s[TOPK], keep[TOPK];
  __shared__ uint32_t s_cnt, s_thr;

  // sum the 17 chunk histograms
  uint32_t v = 0;
  for (int c = 0; c < NCHUNK; ++c) v += hist[((size_t)b * NCHUNK + c) * 256 + t];
  tot[t] = v;
  if (t == 0) s_cnt = 0;
  __syncthreads();

  // inclusive suffix sum over 256 bins (Hillis-Steele, 8 steps)
  for (int d = 1; d < 256; d <<= 1) {
    uint32_t add = (t + d < 256) ? tot[t + d] : 0u;
    __syncthreads();
    tot[t] += add;
    __syncthreads();
  }
  // threshold bin: largest t with suffix >= TOPK
  {
    uint32_t suf = tot[t];
    uint32_t sufn = (t < 255) ? tot[t + 1] : 0u;
    if (suf >= TOPK && sufn < TOPK) s_thr = KBASE + ((uint32_t)t << 16);
    if (t == 0 && tot[0] < TOPK) s_thr = KBASE;   // fewer than 100 fg total
  }
  __syncthreads();

  // collect candidates >= threshold into LDS (recompute keys; cls is L2/L3-warm)
  uint32_t th = s_thr;
  for (int n = t; n < N_ANCH; n += 256) {
    uint32_t key = anchor_key(p, b, n);
    if (key >= th) {
      uint32_t pos = atomicAdd(&s_cnt, 1u);
      if (pos < CAP)
        s[pos] = ((unsigned long long)key << 32) | (uint32_t)(~(uint32_t)n);
    }
  }
  __syncthreads();
  int c = (int)min(s_cnt, (uint32_t)CAP);
  int P = 128;
  while (P < c) P <<= 1;
  for (int i = t; i < P; i += 256)
    if (i >= c) s[i] = 0ull;
  __syncthreads();

  // bitonic sort ascending; rank r lives at s[P-1-r]
  for (int k = 2; k <= P; k <<= 1) {
    for (int j = k >> 1; j > 0; j >>= 1) {
      for (int i = t; i < P; i += 256) {
        int ixj = i ^ j;
        if (ixj > i) {
          unsigned long long a = s[i], bb = s[ixj];
          bool up = ((i & k) == 0);
          if ((a > bb) == up) { s[i] = bb; s[ixj] = a; }
        }
      }
      __syncthreads();
    }
  }

  // decode top-100
  int r = t;
  if (r < TOPK) {
    unsigned long long pk = s[P - 1 - r];
    if (pk == 0ull) {
      sc[r] = -1.f; cls_s[r] = 0; keep[r] = 0;
      bx1[r] = by1[r] = bx2[r] = by2[r] = 0.f; area[r] = 1.f;
    } else {
      uint32_t key = (uint32_t)(pk >> 32);
      int n = (int)(~(uint32_t)pk);
      float score = __uint_as_float(key & 0x7FFFFFFFu);
      int k2 = 0;
#pragma unroll
      for (int q = 1; q < 8; ++q) if (n >= c_off[q]) k2 = q;
      int local = n - c_off[k2];
      int w = c_sz[k2], hw = w * w;
      int i2 = local / w, j2 = local % w;
      const float* cp = p.cls[k2] + (size_t)(b * 3) * hw + local;
      float l0 = cp[0], l1 = cp[(size_t)hw], l2 = cp[(size_t)2 * hw];
      float m = l0; int cl = 0;
      if (l1 > m) { m = l1; cl = 1; }
      if (l2 > m) { m = l2; cl = 2; }
      const float* rp = p.reg[k2] + (size_t)(b * 4) * hw + local;
      float r0 = rp[0], r1 = rp[(size_t)hw], r2 = rp[(size_t)2 * hw], r3 = rp[(size_t)3 * hw];
      float st = c_st[k2], rf = c_rf[k2];
      float cx = (float)j2 * st + st * 0.5f;
      float cy = (float)i2 * st + st * 0.5f;
      float x1 = cx - r0 * rf, y1 = cy - r1 * rf;
      float x2 = cx + r2 * rf, y2 = cy + r3 * rf;
      sc[r] = score; cls_s[r] = cl;
      bx1[r] = x1; by1[r] = y1; bx2[r] = x2; by2[r] = y2;
      area[r] = (x2 - x1 + 1.0f) * (y2 - y1 + 1.0f);
      keep[r] = (score >= 0.35f && cl > 0) ? 1 : 0;
    }
  }
  __syncthreads();

  // greedy NMS in a single wave: lane l owns ranks l and l+64; zero barriers
  if (t < 64) {
    int r0 = t, r1 = t + 64;
    float a1x = bx1[r0], a1y = by1[r0], a2x = bx2[r0], a2y = by2[r0], aA = area[r0];
    int k0 = keep[r0];
    bool has1 = (r1 < TOPK);
    float c1x = 0.f, c1y = 0.f, c2x = 0.f, c2y = 0.f, cA = 1.f;
    int k1 = 0;
    if (has1) { c1x = bx1[r1]; c1y = by1[r1]; c2x = bx2[r1]; c2y = by2[r1]; cA = area[r1]; k1 = keep[r1]; }
    for (int i = 0; i < TOPK; ++i) {
      int ol = i & 63, sl = i >> 6;
      int   ki  = __shfl(sl ? k1  : k0,  ol);
      float ix1 = __shfl(sl ? c1x : a1x, ol);
      float iy1 = __shfl(sl ? c1y : a1y, ol);
      float ix2 = __shfl(sl ? c2x : a2x, ol);
      float iy2 = __shfl(sl ? c2y : a2y, ol);
      float iA  = __shfl(sl ? cA  : aA,  ol);
      if (ki) {
        if (k0 && r0 > i) {
          float xmin = fmaxf(ix1, a1x), ymin = fmaxf(iy1, a1y);
          float xmax = fminf(ix2, a2x), ymax = fminf(iy2, a2y);
          float inter = fmaxf(xmax - xmin, 0.f) * fmaxf(ymax - ymin, 0.f);
          float iou = inter / (iA + aA - inter);
          if (iou > 0.5f) k0 = 0;
        }
        if (has1 && k1 && r1 > i) {
          float xmin = fmaxf(ix1, c1x), ymin = fmaxf(iy1, c1y);
          float xmax = fminf(ix2, c2x), ymax = fminf(iy2, c2y);
          float inter = fmaxf(xmax - xmin, 0.f) * fmaxf(ymax - ymin, 0.f);
          float iou = inter / (iA + cA - inter);
          if (iou > 0.5f) k1 = 0;
        }
      }
    }
    keep[r0] = k0;
    if (has1) keep[r1] = k1;
  }
  __syncthreads();

  if (r < TOPK) {
    int o = b * TOPK + r;
    bool kp = keep[r] != 0;
    out[o] = kp ? sc[r] : 0.f;                                  // scores
    out[NBATCH * TOPK + o] = kp ? (float)cls_s[r] : 0.f;        // classes
    float* ob = out + 2 * NBATCH * TOPK + (size_t)o * 4;        // boxes
    ob[0] = kp ? bx1[r] : 0.f;
    ob[1] = kp ? by1[r] : 0.f;
    ob[2] = kp ? bx2[r] : 0.f;
    ob[3] = kp ? by2[r] : 0.f;
    out[6 * NBATCH * TOPK + o] = kp ? 1.f : 0.f;                // keep
  }
}

extern "C" void kernel_launch(void* const* d_in, const int* in_sizes, int n_in,
                              void* d_out, int out_size, void* d_ws, size_t ws_size,
                              hipStream_t stream) {
  Ptrs p;
  // setup_inputs() dict order is INTERLEAVED: cls0, reg0, cls1, reg1, ...
  for (int i = 0; i < 8; ++i) {
    p.cls[i] = (const float*)d_in[2 * i];
    p.reg[i] = (const float*)d_in[2 * i + 1];
  }
  uint32_t* hist = (uint32_t*)d_ws;   // 32*17*256*4 = 557056 B (all-stores, no memset)
  float* out = (float*)d_out;

  k_hist<<<NBATCH * NCHUNK, 256, 0, stream>>>(p, hist);
  k_final<<<NBATCH, 256, 0, stream>>>(p, hist, out);
}

// Round 3
// 92.352 us; speedup vs baseline: 2.6768x; 2.6768x over previous
//
#include <hip/hip_runtime.h>
#include <stdint.h>

#define N_ANCH  65648
#define NQUAD   (N_ANCH / 4)   // 16412 (65648 % 4 == 0)
#define K1CHUNK 1024
#define K1NCH   65             // ceil(65648/1024)
#define CAP     4096
#define KBASE   0xBE800000u    // sortable key of score 0.25 (fg scores >= 1/3 -> bins >= 42)
#define NBATCH  32
#define TOPK    100

struct Ptrs { const float* cls[8]; const float* reg[8]; };

__constant__ int   c_off[9] = {0,25281,50562,56803,63044,64565,64926,65287,65648};
__constant__ int   c_sz[8]  = {159,159,79,79,39,19,19,19};
__constant__ float c_st[8]  = {4.f,4.f,8.f,8.f,16.f,32.f,32.f,32.f};
__constant__ float c_rf[8]  = {27.5f,35.5f,55.5f,71.5f,111.5f,191.5f,255.5f,319.5f};

// sortable key for the masked score of anchor n in batch b; 0 if background.
// EXACT same fp sequence as the numpy reference -> deterministic, reproducible bits.
__device__ inline uint32_t anchor_key(const Ptrs& p, int b, int n) {
  int k = 0;
#pragma unroll
  for (int q = 1; q < 8; ++q) if (n >= c_off[q]) k = q;
  int local = n - c_off[k];
  int hw = c_sz[k] * c_sz[k];
  const float* c = p.cls[k] + (size_t)(b * 3) * hw + local;
  float l0 = c[0], l1 = c[(size_t)hw], l2 = c[(size_t)2 * hw];
  float m = l0; int cl = 0;
  if (l1 > m) { m = l1; cl = 1; }
  if (l2 > m) { m = l2; cl = 2; }
  if (cl == 0) return 0u;
  float s = 1.0f / (expf(l0 - m) + expf(l1 - m) + expf(l2 - m));
  return __float_as_uint(s) | 0x80000000u; // positive float -> monotonic uint
}

// Pass 1 (WIDE): one anchor_key evaluation per anchor, store 8-bit bin.
__global__ __launch_bounds__(256) void k_bins(Ptrs p, uint8_t* bins) {
  int bid = blockIdx.x;
  int b = bid / K1NCH, chunk = bid % K1NCH;
  int n0 = chunk * K1CHUNK + threadIdx.x * 4;
  if (n0 >= N_ANCH) return;   // 65648 % 4 == 0 -> threads fully in or fully out
  uchar4 v;
  uint8_t* vb = (uint8_t*)&v;
#pragma unroll
  for (int j = 0; j < 4; ++j) {
    uint32_t key = anchor_key(p, b, n0 + j);
    vb[j] = key ? (uint8_t)((key - KBASE) >> 16) : (uint8_t)0; // fg bins in [42,255]
  }
  *(uchar4*)(bins + (size_t)b * N_ANCH + n0) = v;
}

// Pass 2: one block per batch — hist, threshold, collect, exact keys, sort, NMS, out.
__global__ __launch_bounds__(256) void k_final(Ptrs p, const uint8_t* bins, float* out) {
  int b = blockIdx.x, t = threadIdx.x;
  __shared__ uint32_t lh[8 * 257];     // 8 replicas, stride 257 (bank stagger)
  __shared__ uint32_t tot[256];
  __shared__ unsigned long long s[CAP];
  __shared__ float bx1[TOPK], by1[TOPK], bx2[TOPK], by2[TOPK], area[TOPK], sc[TOPK];
  __shared__ int cls_s[TOPK], keep[TOPK];
  __shared__ uint32_t s_cnt;
  __shared__ int s_thr;

  for (int i = t; i < 8 * 257; i += 256) lh[i] = 0;
  if (t == 0) s_cnt = 0;
  __syncthreads();

  const uchar4* bp = (const uchar4*)(bins + (size_t)b * N_ANCH);
  int rep = (t & 7) * 257;
  for (int i = t; i < NQUAD; i += 256) {
    uchar4 v = bp[i];
    if (v.x) atomicAdd(&lh[rep + v.x], 1u);
    if (v.y) atomicAdd(&lh[rep + v.y], 1u);
    if (v.z) atomicAdd(&lh[rep + v.z], 1u);
    if (v.w) atomicAdd(&lh[rep + v.w], 1u);
  }
  __syncthreads();
  uint32_t sum = 0;
#pragma unroll
  for (int r = 0; r < 8; ++r) sum += lh[r * 257 + t];
  tot[t] = sum;
  __syncthreads();

  // inclusive suffix sum over 256 bins (Hillis-Steele)
  for (int d = 1; d < 256; d <<= 1) {
    uint32_t add = (t + d < 256) ? tot[t + d] : 0u;
    __syncthreads();
    tot[t] += add;
    __syncthreads();
  }
  {
    uint32_t suf = tot[t];
    uint32_t sufn = (t < 255) ? tot[t + 1] : 0u;
    if (suf >= TOPK && sufn < TOPK) s_thr = t;   // exactly one setter
    if (t == 0 && tot[0] < TOPK) s_thr = 0;      // fewer than 100 fg total
  }
  __syncthreads();
  int thr = s_thr; if (thr < 1) thr = 1;         // v>=1 <=> foreground

  // collect candidate indices (bins are L1/L2-warm from the hist scan)
  for (int i = t; i < NQUAD; i += 256) {
    uchar4 v = bp[i];
    if (v.x >= thr) { uint32_t q = atomicAdd(&s_cnt, 1u); if (q < CAP) s[q] = (unsigned long long)(i * 4 + 0); }
    if (v.y >= thr) { uint32_t q = atomicAdd(&s_cnt, 1u); if (q < CAP) s[q] = (unsigned long long)(i * 4 + 1); }
    if (v.z >= thr) { uint32_t q = atomicAdd(&s_cnt, 1u); if (q < CAP) s[q] = (unsigned long long)(i * 4 + 2); }
    if (v.w >= thr) { uint32_t q = atomicAdd(&s_cnt, 1u); if (q < CAP) s[q] = (unsigned long long)(i * 4 + 3); }
  }
  __syncthreads();
  int c = (int)min(s_cnt, (uint32_t)CAP);

  // exact keys only for ~O(100s) candidates
  for (int i = t; i < c; i += 256) {
    int n = (int)s[i];
    uint32_t key = anchor_key(p, b, n);
    s[i] = ((unsigned long long)key << 32) | (uint32_t)(~(uint32_t)n);
  }
  int P = 128;
  while (P < c) P <<= 1;
  for (int i = t; i < P; i += 256)
    if (i >= c) s[i] = 0ull;
  __syncthreads();

  // bitonic sort ascending; rank r lives at s[P-1-r]
  for (int k = 2; k <= P; k <<= 1) {
    for (int j = k >> 1; j > 0; j >>= 1) {
      for (int i = t; i < P; i += 256) {
        int ixj = i ^ j;
        if (ixj > i) {
          unsigned long long a = s[i], bb = s[ixj];
          bool up = ((i & k) == 0);
          if ((a > bb) == up) { s[i] = bb; s[ixj] = a; }
        }
      }
      __syncthreads();
    }
  }

  // decode top-100
  int r = t;
  if (r < TOPK) {
    unsigned long long pk = s[P - 1 - r];
    if (pk == 0ull) {
      sc[r] = -1.f; cls_s[r] = 0; keep[r] = 0;
      bx1[r] = by1[r] = bx2[r] = by2[r] = 0.f; area[r] = 1.f;
    } else {
      uint32_t key = (uint32_t)(pk >> 32);
      int n = (int)(~(uint32_t)pk);
      float score = __uint_as_float(key & 0x7FFFFFFFu);
      int k2 = 0;
#pragma unroll
      for (int q = 1; q < 8; ++q) if (n >= c_off[q]) k2 = q;
      int local = n - c_off[k2];
      int w = c_sz[k2], hw = w * w;
      int i2 = local / w, j2 = local % w;
      const float* cp = p.cls[k2] + (size_t)(b * 3) * hw + local;
      float l0 = cp[0], l1 = cp[(size_t)hw], l2 = cp[(size_t)2 * hw];
      float m = l0; int cl = 0;
      if (l1 > m) { m = l1; cl = 1; }
      if (l2 > m) { m = l2; cl = 2; }
      const float* rp = p.reg[k2] + (size_t)(b * 4) * hw + local;
      float r0 = rp[0], r1 = rp[(size_t)hw], r2 = rp[(size_t)2 * hw], r3 = rp[(size_t)3 * hw];
      float st = c_st[k2], rf = c_rf[k2];
      float cx = (float)j2 * st + st * 0.5f;
      float cy = (float)i2 * st + st * 0.5f;
      float x1 = cx - r0 * rf, y1 = cy - r1 * rf;
      float x2 = cx + r2 * rf, y2 = cy + r3 * rf;
      sc[r] = score; cls_s[r] = cl;
      bx1[r] = x1; by1[r] = y1; bx2[r] = x2; by2[r] = y2;
      area[r] = (x2 - x1 + 1.0f) * (y2 - y1 + 1.0f);
      keep[r] = (score >= 0.35f && cl > 0) ? 1 : 0;
    }
  }
  __syncthreads();

  // greedy NMS in a single wave: lane l owns ranks l and l+64; zero barriers
  if (t < 64) {
    int r0 = t, r1 = t + 64;
    float a1x = bx1[r0], a1y = by1[r0], a2x = bx2[r0], a2y = by2[r0], aA = area[r0];
    int k0 = keep[r0];
    bool has1 = (r1 < TOPK);
    float c1x = 0.f, c1y = 0.f, c2x = 0.f, c2y = 0.f, cA = 1.f;
    int k1 = 0;
    if (has1) { c1x = bx1[r1]; c1y = by1[r1]; c2x = bx2[r1]; c2y = by2[r1]; cA = area[r1]; k1 = keep[r1]; }
    for (int i = 0; i < TOPK; ++i) {
      int ol = i & 63, sl = i >> 6;
      int   ki  = __shfl(sl ? k1  : k0,  ol);
      float ix1 = __shfl(sl ? c1x : a1x, ol);
      float iy1 = __shfl(sl ? c1y : a1y, ol);
      float ix2 = __shfl(sl ? c2x : a2x, ol);
      float iy2 = __shfl(sl ? c2y : a2y, ol);
      float iA  = __shfl(sl ? cA  : aA,  ol);
      if (ki) {
        if (k0 && r0 > i) {
          float xmin = fmaxf(ix1, a1x), ymin = fmaxf(iy1, a1y);
          float xmax = fminf(ix2, a2x), ymax = fminf(iy2, a2y);
          float inter = fmaxf(xmax - xmin, 0.f) * fmaxf(ymax - ymin, 0.f);
          float iou = inter / (iA + aA - inter);
          if (iou > 0.5f) k0 = 0;
        }
        if (has1 && k1 && r1 > i) {
          float xmin = fmaxf(ix1, c1x), ymin = fmaxf(iy1, c1y);
          float xmax = fminf(ix2, c2x), ymax = fminf(iy2, c2y);
          float inter = fmaxf(xmax - xmin, 0.f) * fmaxf(ymax - ymin, 0.f);
          float iou = inter / (iA + cA - inter);
          if (iou > 0.5f) k1 = 0;
        }
      }
    }
    keep[r0] = k0;
    if (has1) keep[r1] = k1;
  }
  __syncthreads();

  if (r < TOPK) {
    int o = b * TOPK + r;
    bool kp = keep[r] != 0;
    out[o] = kp ? sc[r] : 0.f;                                  // scores
    out[NBATCH * TOPK + o] = kp ? (float)cls_s[r] : 0.f;        // classes
    float* ob = out + 2 * NBATCH * TOPK + (size_t)o * 4;        // boxes
    ob[0] = kp ? bx1[r] : 0.f;
    ob[1] = kp ? by1[r] : 0.f;
    ob[2] = kp ? bx2[r] : 0.f;
    ob[3] = kp ? by2[r] : 0.f;
    out[6 * NBATCH * TOPK + o] = kp ? 1.f : 0.f;                // keep
  }
}

extern "C" void kernel_launch(void* const* d_in, const int* in_sizes, int n_in,
                              void* d_out, int out_size, void* d_ws, size_t ws_size,
                              hipStream_t stream) {
  Ptrs p;
  // setup_inputs() dict order is INTERLEAVED: cls0, reg0, cls1, reg1, ...
  for (int i = 0; i < 8; ++i) {
    p.cls[i] = (const float*)d_in[2 * i];
    p.reg[i] = (const float*)d_in[2 * i + 1];
  }
  uint8_t* bins = (uint8_t*)d_ws;   // 32*65648 = 2,100,736 B; fully overwritten each call
  float* out = (float*)d_out;

  k_bins<<<NBATCH * K1NCH, 256, 0, stream>>>(p, bins);
  k_final<<<NBATCH, 256, 0, stream>>>(p, bins, out);
}

// Round 4
// 80.933 us; speedup vs baseline: 3.0545x; 1.1411x over previous
//
#include <hip/hip_runtime.h>
#include <stdint.h>

#define N_ANCH 65648
#define NCHUNK 17          // chunks of 4096 anchors
#define CHUNK  4096
#define CAP    4096
#define KBASE  0xBE800000u // sortable key of 0.25; fg scores >= 1/3 -> bins in [42,255]
#define NBATCH 32
#define TOPK   100

struct Ptrs { const float* cls[8]; const float* reg[8]; };

__constant__ int   c_off[9] = {0,25281,50562,56803,63044,64565,64926,65287,65648};
__constant__ int   c_sz[8]  = {159,159,79,79,39,19,19,19};
__constant__ float c_st[8]  = {4.f,4.f,8.f,8.f,16.f,32.f,32.f,32.f};
__constant__ float c_rf[8]  = {27.5f,35.5f,55.5f,71.5f,111.5f,191.5f,255.5f,319.5f};

// sortable key for the masked score of anchor n in batch b; 0 if background.
__device__ inline uint32_t anchor_key(const Ptrs& p, int b, int n) {
  int k = 0;
#pragma unroll
  for (int q = 1; q < 8; ++q) if (n >= c_off[q]) k = q;
  int local = n - c_off[k];
  int hw = c_sz[k] * c_sz[k];
  const float* c = p.cls[k] + (size_t)(b * 3) * hw + local;
  float l0 = c[0], l1 = c[(size_t)hw], l2 = c[(size_t)2 * hw];
  float m = l0; int cl = 0;
  if (l1 > m) { m = l1; cl = 1; }
  if (l2 > m) { m = l2; cl = 2; }
  if (cl == 0) return 0u;
  float s = 1.0f / (expf(l0 - m) + expf(l1 - m) + expf(l2 - m));
  return __float_as_uint(s) | 0x80000000u; // positive float -> monotonic uint
}

// K1 (WIDE): u8 bins + per-(batch,chunk) histogram (pure stores) + zero counters
__global__ __launch_bounds__(256) void k_bins(Ptrs p, uint8_t* bins, uint32_t* hist,
                                              uint32_t* counter) {
  int bid = blockIdx.x;
  int b = bid / NCHUNK, chunk = bid % NCHUNK;
  int t = threadIdx.x;
  __shared__ uint32_t lh[256];
  lh[t] = 0;
  if (chunk == 0 && t == 0) counter[b] = 0;   // visible to K2 via kernel boundary
  __syncthreads();
  int base = chunk * CHUNK;
#pragma unroll
  for (int j = 0; j < 4; ++j) {
    int n0 = base + j * 1024 + t * 4;
    if (n0 < N_ANCH) {                         // quads never straddle N_ANCH (65648%4==0)
      uchar4 v; uint8_t* vb = (uint8_t*)&v;
#pragma unroll
      for (int u = 0; u < 4; ++u) {
        uint32_t key = anchor_key(p, b, n0 + u);
        uint8_t bin = key ? (uint8_t)((key - KBASE) >> 16) : (uint8_t)0;
        vb[u] = bin;
        if (bin) atomicAdd(&lh[bin], 1u);
      }
      *(uchar4*)(bins + (size_t)b * N_ANCH + n0) = v;
    }
  }
  __syncthreads();
  hist[((size_t)b * NCHUNK + chunk) * 256 + t] = lh[t];
}

// K2 (WIDE): per-block redundant threshold from chunk-hists, then append candidates
__global__ __launch_bounds__(256) void k_collect(const uint8_t* bins, const uint32_t* hist,
                                                 uint32_t* counter, uint32_t* cand) {
  int bid = blockIdx.x;
  int b = bid / NCHUNK, chunk = bid % NCHUNK;
  int t = threadIdx.x;
  __shared__ uint32_t tot[256];
  __shared__ int s_thr;
  uint32_t v = 0;
  for (int ch = 0; ch < NCHUNK; ++ch) v += hist[((size_t)b * NCHUNK + ch) * 256 + t];
  tot[t] = v;
  __syncthreads();
  for (int d = 1; d < 256; d <<= 1) {          // inclusive suffix sum
    uint32_t add = (t + d < 256) ? tot[t + d] : 0u;
    __syncthreads();
    tot[t] += add;
    __syncthreads();
  }
  uint32_t suf = tot[t], sufn = (t < 255) ? tot[t + 1] : 0u;
  if (suf >= TOPK && sufn < TOPK) s_thr = t;   // exactly one setter
  if (t == 0 && tot[0] < TOPK) s_thr = 0;
  __syncthreads();
  int thr = s_thr; if (thr < 1) thr = 1;       // bin>=1 <=> foreground

  int base = chunk * CHUNK;
  const uint8_t* bb = bins + (size_t)b * N_ANCH;
#pragma unroll
  for (int j = 0; j < 4; ++j) {
    int n0 = base + j * 1024 + t * 4;
    if (n0 < N_ANCH) {
      uchar4 v4 = *(const uchar4*)(bb + n0);
      if (v4.x >= thr) { uint32_t q = atomicAdd(&counter[b], 1u); if (q < CAP) cand[(size_t)b * CAP + q] = n0 + 0; }
      if (v4.y >= thr) { uint32_t q = atomicAdd(&counter[b], 1u); if (q < CAP) cand[(size_t)b * CAP + q] = n0 + 1; }
      if (v4.z >= thr) { uint32_t q = atomicAdd(&counter[b], 1u); if (q < CAP) cand[(size_t)b * CAP + q] = n0 + 2; }
      if (v4.w >= thr) { uint32_t q = atomicAdd(&counter[b], 1u); if (q < CAP) cand[(size_t)b * CAP + q] = n0 + 3; }
    }
  }
}

// K3: one block per batch, strictly O(CAP) work: exact keys, sort, decode, NMS, out
__global__ __launch_bounds__(512) void k_final(Ptrs p, const uint32_t* counter,
                                               const uint32_t* cand, float* out) {
  int b = blockIdx.x, t = threadIdx.x;
  __shared__ unsigned long long s[CAP];
  __shared__ float bx1[TOPK], by1[TOPK], bx2[TOPK], by2[TOPK], area[TOPK], sc[TOPK];
  __shared__ int cls_s[TOPK], keep[TOPK];

  int c = (int)min(counter[b], (uint32_t)CAP);
  for (int i = t; i < c; i += 512) {
    int n = (int)cand[(size_t)b * CAP + i];
    uint32_t key = anchor_key(p, b, n);        // cls is L2/L3-warm
    s[i] = ((unsigned long long)key << 32) | (uint32_t)(~(uint32_t)n);
  }
  int P = 128;
  while (P < c) P <<= 1;
  for (int i = t; i < P; i += 512)
    if (i >= c) s[i] = 0ull;
  __syncthreads();

  // bitonic sort ascending; rank r lives at s[P-1-r]
  for (int k = 2; k <= P; k <<= 1) {
    for (int j = k >> 1; j > 0; j >>= 1) {
      for (int i = t; i < P; i += 512) {
        int ixj = i ^ j;
        if (ixj > i) {
          unsigned long long a = s[i], bb = s[ixj];
          bool up = ((i & k) == 0);
          if ((a > bb) == up) { s[i] = bb; s[ixj] = a; }
        }
      }
      __syncthreads();
    }
  }

  // decode top-100
  int r = t;
  if (r < TOPK) {
    unsigned long long pk = s[P - 1 - r];
    if (pk == 0ull) {
      sc[r] = -1.f; cls_s[r] = 0; keep[r] = 0;
      bx1[r] = by1[r] = bx2[r] = by2[r] = 0.f; area[r] = 1.f;
    } else {
      uint32_t key = (uint32_t)(pk >> 32);
      int n = (int)(~(uint32_t)pk);
      float score = __uint_as_float(key & 0x7FFFFFFFu);
      int k2 = 0;
#pragma unroll
      for (int q = 1; q < 8; ++q) if (n >= c_off[q]) k2 = q;
      int local = n - c_off[k2];
      int w = c_sz[k2], hw = w * w;
      int i2 = local / w, j2 = local % w;
      const float* cp = p.cls[k2] + (size_t)(b * 3) * hw + local;
      float l0 = cp[0], l1 = cp[(size_t)hw], l2 = cp[(size_t)2 * hw];
      float m = l0; int cl = 0;
      if (l1 > m) { m = l1; cl = 1; }
      if (l2 > m) { m = l2; cl = 2; }
      const float* rp = p.reg[k2] + (size_t)(b * 4) * hw + local;
      float r0 = rp[0], r1 = rp[(size_t)hw], r2 = rp[(size_t)2 * hw], r3 = rp[(size_t)3 * hw];
      float st = c_st[k2], rf = c_rf[k2];
      float cx = (float)j2 * st + st * 0.5f;
      float cy = (float)i2 * st + st * 0.5f;
      float x1 = cx - r0 * rf, y1 = cy - r1 * rf;
      float x2 = cx + r2 * rf, y2 = cy + r3 * rf;
      sc[r] = score; cls_s[r] = cl;
      bx1[r] = x1; by1[r] = y1; bx2[r] = x2; by2[r] = y2;
      area[r] = (x2 - x1 + 1.0f) * (y2 - y1 + 1.0f);
      keep[r] = (score >= 0.35f && cl > 0) ? 1 : 0;
    }
  }
  __syncthreads();

  // greedy NMS in a single wave: lane l owns ranks l and l+64; zero barriers
  if (t < 64) {
    int r0 = t, r1 = t + 64;
    float a1x = bx1[r0], a1y = by1[r0], a2x = bx2[r0], a2y = by2[r0], aA = area[r0];
    int k0 = keep[r0];
    bool has1 = (r1 < TOPK);
    float c1x = 0.f, c1y = 0.f, c2x = 0.f, c2y = 0.f, cA = 1.f;
    int k1 = 0;
    if (has1) { c1x = bx1[r1]; c1y = by1[r1]; c2x = bx2[r1]; c2y = by2[r1]; cA = area[r1]; k1 = keep[r1]; }
    for (int i = 0; i < TOPK; ++i) {
      int ol = i & 63, sl = i >> 6;
      int   ki  = __shfl(sl ? k1  : k0,  ol);
      float ix1 = __shfl(sl ? c1x : a1x, ol);
      float iy1 = __shfl(sl ? c1y : a1y, ol);
      float ix2 = __shfl(sl ? c2x : a2x, ol);
      float iy2 = __shfl(sl ? c2y : a2y, ol);
      float iA  = __shfl(sl ? cA  : aA,  ol);
      if (ki) {
        if (k0 && r0 > i) {
          float xmin = fmaxf(ix1, a1x), ymin = fmaxf(iy1, a1y);
          float xmax = fminf(ix2, a2x), ymax = fminf(iy2, a2y);
          float inter = fmaxf(xmax - xmin, 0.f) * fmaxf(ymax - ymin, 0.f);
          float iou = inter / (iA + aA - inter);
          if (iou > 0.5f) k0 = 0;
        }
        if (has1 && k1 && r1 > i) {
          float xmin = fmaxf(ix1, c1x), ymin = fmaxf(iy1, c1y);
          float xmax = fminf(ix2, c2x), ymax = fminf(iy2, c2y);
          float inter = fmaxf(xmax - xmin, 0.f) * fmaxf(ymax - ymin, 0.f);
          float iou = inter / (iA + cA - inter);
          if (iou > 0.5f) k1 = 0;
        }
      }
    }
    keep[r0] = k0;
    if (has1) keep[r1] = k1;
  }
  __syncthreads();

  if (r < TOPK) {
    int o = b * TOPK + r;
    bool kp = keep[r] != 0;
    out[o] = kp ? sc[r] : 0.f;                                  // scores
    out[NBATCH * TOPK + o] = kp ? (float)cls_s[r] : 0.f;        // classes
    float* ob = out + 2 * NBATCH * TOPK + (size_t)o * 4;        // boxes
    ob[0] = kp ? bx1[r] : 0.f;
    ob[1] = kp ? by1[r] : 0.f;
    ob[2] = kp ? bx2[r] : 0.f;
    ob[3] = kp ? by2[r] : 0.f;
    out[6 * NBATCH * TOPK + o] = kp ? 1.f : 0.f;                // keep
  }
}

extern "C" void kernel_launch(void* const* d_in, const int* in_sizes, int n_in,
                              void* d_out, int out_size, void* d_ws, size_t ws_size,
                              hipStream_t stream) {
  Ptrs p;
  // setup_inputs() dict order is INTERLEAVED: cls0, reg0, cls1, reg1, ...
  for (int i = 0; i < 8; ++i) {
    p.cls[i] = (const float*)d_in[2 * i];
    p.reg[i] = (const float*)d_in[2 * i + 1];
  }
  uint8_t*  bins    = (uint8_t*)d_ws;                            // 2,100,736 B
  uint32_t* hist    = (uint32_t*)((char*)d_ws + 2100736);        // 32*17*256*4 = 557,056 B
  uint32_t* counter = (uint32_t*)((char*)d_ws + 2657792);        // 128 B
  uint32_t* cand    = (uint32_t*)((char*)d_ws + 2657920);        // 32*4096*4 = 524,288 B
  float* out = (float*)d_out;                                    // total ws: ~3.18 MB

  k_bins<<<NBATCH * NCHUNK, 256, 0, stream>>>(p, bins, hist, counter);
  k_collect<<<NBATCH * NCHUNK, 256, 0, stream>>>(bins, hist, counter, cand);
  k_final<<<NBATCH, 512, 0, stream>>>(p, counter, cand, out);
}